// Round 11
// baseline (283.136 us; speedup 1.0000x reference)
//
#include <hip/hip_runtime.h>
#include <hip/hip_fp16.h>

#define NN 50000
#define NE 800000
#define NG 64
#define DF 96
#define SLOPE 0.2f
#define NBK 196   // (NN+255)/256 buckets of 256 dst nodes
#define EB 196    // (NE+4095)/4096 edge blocks (4096 edges per block)
#define PC 12     // pool chunks per graph

// ---------------- pass A1: per-block bucket histogram (row-major out, coalesced) ----------------
__global__ __launch_bounds__(256) void k_hist(const int* __restrict__ dst,
                                              int* __restrict__ hist2d) {
  __shared__ int h[NBK];
  int t = threadIdx.x;
  if (t < NBK) h[t] = 0;
  __syncthreads();
  int base = blockIdx.x * 4096;
  for (int k = 0; k < 16; ++k) {
    int e = base + k * 256 + t;
    if (e < NE) atomicAdd(&h[dst[e] >> 8], 1);
  }
  __syncthreads();
  if (t < NBK) hist2d[blockIdx.x * NBK + t] = h[t];
}

// ---------------- per-column exclusive scan over edge-blocks; block 0: graph bounds + zero-inits --
__global__ __launch_bounds__(256) void k_colscan(const int* __restrict__ hist2d,
                                                 int* __restrict__ colpref,
                                                 int* __restrict__ coltotal,
                                                 const int* __restrict__ batch,
                                                 int* __restrict__ gstart,
                                                 int* __restrict__ deghist,
                                                 int* __restrict__ classcnt) {
  __shared__ int s[256];
  int col = blockIdx.x;  // bucket (column)
  int b = threadIdx.x;   // edge-block index
  int v = (b < EB) ? hist2d[b * NBK + col] : 0;
  s[b] = v;
  __syncthreads();
  for (int o = 1; o < 256; o <<= 1) {
    int u = (b >= o) ? s[b - o] : 0;
    __syncthreads();
    s[b] += u;
    __syncthreads();
  }
  if (b < EB) colpref[b * NBK + col] = s[b] - v;
  if (b == 255) coltotal[col] = s[b];
  if (blockIdx.x == 0) {
    deghist[b] = 0;
    classcnt[b] = 0;
    if (b <= NG) {  // graph bounds (batch sorted)
      int g = b, lo = 0, hi = NN;
      while (lo < hi) {
        int mid = (lo + hi) >> 1;
        if (batch[mid] < g) lo = mid + 1; else hi = mid;
      }
      gstart[g] = lo;
    }
  }
}

// ---------------- pass A2: bin edges (deterministic offsets, LDS staged) ----------------
// packed entry: src | ((dst&255)<<16)
__global__ __launch_bounds__(256) void k_bin2(const int* __restrict__ src,
                                              const int* __restrict__ dst,
                                              const int* __restrict__ hist2d,
                                              const int* __restrict__ coltotal,
                                              const int* __restrict__ colpref,
                                              int* __restrict__ binned) {
  __shared__ int h[NBK], loff[NBK], cur[NBK], gb[NBK];
  __shared__ int tmp[256];
  __shared__ int stage[4096];
  __shared__ unsigned char sbk[4096];
  int t = threadIdx.x;
  int ctv = (t < NBK) ? coltotal[t] : 0;
  tmp[t] = ctv;
  __syncthreads();
  for (int o = 1; o < 256; o <<= 1) {
    int u = (t >= o) ? tmp[t - o] : 0;
    __syncthreads();
    tmp[t] += u;
    __syncthreads();
  }
  int bbase_t = tmp[t] - ctv;  // exclusive
  if (t < NBK) h[t] = hist2d[blockIdx.x * NBK + t];
  __syncthreads();
  tmp[t] = (t < NBK) ? h[t] : 0;
  __syncthreads();
  for (int o = 1; o < 256; o <<= 1) {
    int u = (t >= o) ? tmp[t - o] : 0;
    __syncthreads();
    tmp[t] += u;
    __syncthreads();
  }
  if (t < NBK) {
    int excl = tmp[t] - h[t];
    loff[t] = excl;
    cur[t] = excl;
    gb[t] = bbase_t + colpref[blockIdx.x * NBK + t];
  }
  __syncthreads();
  int base = blockIdx.x * 4096;
  for (int k = 0; k < 16; ++k) {
    int e = base + k * 256 + t;
    if (e < NE) {
      int d = dst[e];
      int b = d >> 8;
      int p = atomicAdd(&cur[b], 1);
      stage[p] = src[e] | ((d & 255) << 16);
      sbk[p] = (unsigned char)b;
    }
  }
  __syncthreads();
  int tot = min(4096, NE - base);
  for (int i = t; i < tot; i += 256) {
    int b = sbk[i];
    binned[gb[b] + (i - loff[b])] = stage[i];
  }
}

// ---------------- pass B: per-bucket CSR build + dinv/row_start + degree histogram ----------------
__global__ __launch_bounds__(256) void k_csr(const int* __restrict__ binned,
                                             const int* __restrict__ coltotal,
                                             float* __restrict__ dinv,
                                             int* __restrict__ row_start,
                                             unsigned short* __restrict__ csr_src,
                                             unsigned char* __restrict__ deg8,
                                             int* __restrict__ deghist) {
  __shared__ int h[256], cur[256], tmp[256], dh[256];
  int t = threadIdx.x;
  int b = blockIdx.x;
  int ctv = (t < NBK) ? coltotal[t] : 0;
  h[t] = ctv;
  tmp[t] = ctv;
  __syncthreads();
  for (int o = 1; o < 256; o <<= 1) {
    int u = (t >= o) ? tmp[t - o] : 0;
    __syncthreads();
    tmp[t] += u;
    __syncthreads();
  }
  int ebeg = tmp[b] - h[b];
  int eend = tmp[b];
  __syncthreads();
  h[t] = 0;
  dh[t] = 0;
  __syncthreads();
  for (int i = ebeg + t; i < eend; i += 256) atomicAdd(&h[(unsigned)binned[i] >> 16], 1);
  __syncthreads();
  tmp[t] = h[t];
  __syncthreads();
  for (int o = 1; o < 256; o <<= 1) {
    int v = (t >= o) ? tmp[t - o] : 0;
    __syncthreads();
    tmp[t] += v;
    __syncthreads();
  }
  int mydeg = h[t];
  int rs = ebeg + (tmp[t] - mydeg);
  cur[t] = rs;
  int n = b * 256 + t;
  if (n < NN) {
    row_start[n] = rs;
    dinv[n] = rsqrtf((float)mydeg + 1.0f);
    int c = min(mydeg, 255);
    deg8[n] = (unsigned char)c;
    atomicAdd(&dh[c], 1);
  }
  if (b == NBK - 1 && t == 255) row_start[NN] = NE;
  __syncthreads();
  if (dh[t]) atomicAdd(&deghist[t], dh[t]);
  for (int i = ebeg + t; i < eend; i += 256) {
    int pr = binned[i];
    int p = atomicAdd(&cur[(unsigned)pr >> 16], 1);
    csr_src[p] = (unsigned short)(pr & 0xFFFF);
  }
}

// ---------------- degree-sorted permutation (counting sort; order within class is don't-care) ----
__global__ __launch_bounds__(256) void k_perm(const unsigned char* __restrict__ deg8,
                                              const int* __restrict__ deghist,
                                              int* __restrict__ classcnt,
                                              int* __restrict__ perm) {
  __shared__ int s[256];
  __shared__ int base[256];
  int t = threadIdx.x;
  int v = deghist[t];
  s[t] = v;
  __syncthreads();
  for (int o = 1; o < 256; o <<= 1) {
    int u = (t >= o) ? s[t - o] : 0;
    __syncthreads();
    s[t] += u;
    __syncthreads();
  }
  base[t] = s[t] - v;  // exclusive class base
  __syncthreads();
  int n = blockIdx.x * 256 + t;
  if (n < NN) {
    int c = deg8[n];
    int p = base[c] + atomicAdd(&classcnt[c], 1);
    perm[p] = n;
  }
}

// ---------------- G(fp16) = (X @ W) * dinv[row]; X fp32 or fp16, direct global reads ----------------
#define GR 64
template <typename T>
__global__ __launch_bounds__(256) void k_gemm(const T* __restrict__ X,
                                              const float* __restrict__ W,
                                              const float* __restrict__ dinv,
                                              __half* __restrict__ G) {
  __shared__ float Ws[DF * DF];  // 36.9 KB -> ~4 blocks/CU
  int t = threadIdx.x;
  for (int i = t; i < DF * DF / 4; i += 256)
    ((float4*)Ws)[i] = ((const float4*)W)[i];
  __syncthreads();
  int tc = t & 15;
  int tr = t >> 4;
  int c0 = tc * 6;
  int r0 = blockIdx.x * GR + tr * 4;
  const T* xp[4];
#pragma unroll
  for (int i = 0; i < 4; ++i) xp[i] = X + (size_t)min(r0 + i, NN - 1) * DF;

  float acc[4][6];
#pragma unroll
  for (int i = 0; i < 4; ++i)
#pragma unroll
    for (int j = 0; j < 6; ++j) acc[i][j] = 0.f;

#pragma unroll 4
  for (int k4 = 0; k4 < DF / 4; ++k4) {
    float xr[4][4];
#pragma unroll
    for (int i = 0; i < 4; ++i) {
      if constexpr (sizeof(T) == 4) {
        float4 v = ((const float4*)xp[i])[k4];
        xr[i][0] = v.x; xr[i][1] = v.y; xr[i][2] = v.z; xr[i][3] = v.w;
      } else {
        uint2 hv = ((const uint2*)xp[i])[k4];
        float2 a = __half22float2(*(__half2*)&hv.x);
        float2 b = __half22float2(*(__half2*)&hv.y);
        xr[i][0] = a.x; xr[i][1] = a.y; xr[i][2] = b.x; xr[i][3] = b.y;
      }
    }
#pragma unroll
    for (int kk = 0; kk < 4; ++kk) {
      int k = k4 * 4 + kk;
      float2 w0 = *(float2*)&Ws[k * DF + c0];
      float2 w1 = *(float2*)&Ws[k * DF + c0 + 2];
      float2 w2 = *(float2*)&Ws[k * DF + c0 + 4];
      float wv[6] = {w0.x, w0.y, w1.x, w1.y, w2.x, w2.y};
#pragma unroll
      for (int i = 0; i < 4; ++i)
#pragma unroll
        for (int j = 0; j < 6; ++j) acc[i][j] = fmaf(xr[i][kk], wv[j], acc[i][j]);
    }
  }
#pragma unroll
  for (int i = 0; i < 4; ++i) {
    int row = r0 + i;
    if (row < NN) {
      float dv = dinv[row];
      __half2* gp = (__half2*)(G + (size_t)row * DF + c0);
#pragma unroll
      for (int j = 0; j < 3; ++j)
        gp[j] = __floats2half2_rn(acc[i][2 * j] * dv, acc[i][2 * j + 1] * dv);
    }
  }
}

// ---------------- gather-aggregate: 16 lanes/node (6 feats/lane, 12B loads), degree-sorted -------
__global__ __launch_bounds__(256) void k_agg(const __half* __restrict__ G,
                                             const float* __restrict__ dinv,
                                             const float* __restrict__ bias,
                                             const int* __restrict__ row_start,
                                             const unsigned short* __restrict__ csr_src,
                                             const int* __restrict__ perm,
                                             __half* __restrict__ H) {
  int lane = threadIdx.x & 15;
  int n = perm[blockIdx.x * 16 + (threadIdx.x >> 4)];  // NN = 16*3125 exact
  const char* Gb = (const char*)G;
  uint3 sv = *(const uint3*)(Gb + (size_t)n * 192 + lane * 12);
  float2 f0 = __half22float2(*(__half2*)&sv.x);
  float2 f1 = __half22float2(*(__half2*)&sv.y);
  float2 f2 = __half22float2(*(__half2*)&sv.z);
  float a0 = f0.x, a1 = f0.y, a2 = f1.x, a3 = f1.y, a4 = f2.x, a5 = f2.y;

  int s = row_start[n], e = row_start[n + 1];
  for (int j0 = s; j0 < e; j0 += 16) {
    int my = (j0 + lane < e) ? (int)csr_src[j0 + lane] : 0;
    int cnt = min(16, e - j0);
    int jj = 0;
    for (; jj + 8 <= cnt; jj += 8) {
      uint3 u[8];
#pragma unroll
      for (int q = 0; q < 8; ++q)
        u[q] = *(const uint3*)(Gb + (size_t)__shfl(my, jj + q, 16) * 192 + lane * 12);
#pragma unroll
      for (int q = 0; q < 8; ++q) {
        float2 g0 = __half22float2(*(__half2*)&u[q].x);
        float2 g1 = __half22float2(*(__half2*)&u[q].y);
        float2 g2 = __half22float2(*(__half2*)&u[q].z);
        a0 += g0.x; a1 += g0.y; a2 += g1.x; a3 += g1.y; a4 += g2.x; a5 += g2.y;
      }
    }
    for (; jj < cnt; ++jj) {
      uint3 u = *(const uint3*)(Gb + (size_t)__shfl(my, jj, 16) * 192 + lane * 12);
      float2 g0 = __half22float2(*(__half2*)&u.x);
      float2 g1 = __half22float2(*(__half2*)&u.y);
      float2 g2 = __half22float2(*(__half2*)&u.z);
      a0 += g0.x; a1 += g0.y; a2 += g1.x; a3 += g1.y; a4 += g2.x; a5 += g2.y;
    }
  }
  float dv = dinv[n];
  float2 b0 = *(const float2*)(bias + 6 * lane);
  float2 b1 = *(const float2*)(bias + 6 * lane + 2);
  float2 b2 = *(const float2*)(bias + 6 * lane + 4);
  float v0 = dv * a0 + b0.x, v1 = dv * a1 + b0.y;
  float v2 = dv * a2 + b1.x, v3 = dv * a3 + b1.y;
  float v4 = dv * a4 + b2.x, v5 = dv * a5 + b2.y;
  v0 = v0 > 0.f ? v0 : SLOPE * v0;
  v1 = v1 > 0.f ? v1 : SLOPE * v1;
  v2 = v2 > 0.f ? v2 : SLOPE * v2;
  v3 = v3 > 0.f ? v3 : SLOPE * v3;
  v4 = v4 > 0.f ? v4 : SLOPE * v4;
  v5 = v5 > 0.f ? v5 : SLOPE * v5;
  uint3 o;
  *(__half2*)&o.x = __floats2half2_rn(v0, v1);
  *(__half2*)&o.y = __floats2half2_rn(v2, v3);
  *(__half2*)&o.z = __floats2half2_rn(v4, v5);
  *(uint3*)((char*)H + (size_t)n * 192 + lane * 12) = o;
}

// ---------------- pool stage 1: 12 chunks per graph (fp16 in, fp32 partials) ----------------
__global__ __launch_bounds__(384) void k_pool2(const __half* __restrict__ H,
                                               const int* __restrict__ gstart,
                                               float* __restrict__ partial) {
  int g = blockIdx.x / PC, c = blockIdx.x % PC;
  int f2 = threadIdx.x % 48;
  int r = threadIdx.x / 48;
  int s = gstart[g], e = gstart[g + 1];
  int len = (e - s + PC - 1) / PC;
  int cs = s + c * len, ce = min(cs + len, e);
  float ax = 0.f, ay = 0.f;
  for (int n = cs + r; n < ce; n += 8) {
    float2 v = __half22float2(((const __half2*)(H + (size_t)n * DF))[f2]);
    ax += v.x;
    ay += v.y;
  }
  __shared__ float2 red[8][48];
  red[r][f2] = float2{ax, ay};
  __syncthreads();
  if (r == 0) {
    float sx = 0.f, sy = 0.f;
#pragma unroll
    for (int q = 0; q < 8; ++q) { sx += red[q][f2].x; sy += red[q][f2].y; }
    partial[(size_t)blockIdx.x * DF + 2 * f2] = sx;
    partial[(size_t)blockIdx.x * DF + 2 * f2 + 1] = sy;
  }
}

// ---------------- pool stage 2 + classifier ----------------
__global__ __launch_bounds__(128) void k_pool3(const float* __restrict__ partial,
                                               const int* __restrict__ gstart,
                                               const float* __restrict__ Wc,
                                               const float* __restrict__ bc,
                                               float* __restrict__ out) {
  __shared__ float pm[DF];
  int g = blockIdx.x;
  int t = threadIdx.x;
  if (t < DF) {
    float s = 0.f;
    for (int c = 0; c < PC; ++c) s += partial[(size_t)(g * PC + c) * DF + t];
    float cnt = (float)(gstart[g + 1] - gstart[g]);
    pm[t] = s / fmaxf(cnt, 1.0f);
  }
  __syncthreads();
  if (t < 2) {
    float s = 0.f;
    for (int c = 0; c < DF; ++c) s += pm[c] * Wc[c * 2 + t];
    out[g * 2 + t] = s + bc[t];
  }
}

extern "C" void kernel_launch(void* const* d_in, const int* in_sizes, int n_in,
                              void* d_out, int out_size, void* d_ws, size_t ws_size,
                              hipStream_t stream) {
  const float* x = (const float*)d_in[0];
  const int* ei = (const int*)d_in[1];
  const int* batch = (const int*)d_in[2];
  const float* W1 = (const float*)d_in[3];
  const float* b1 = (const float*)d_in[4];
  const float* W2 = (const float*)d_in[5];
  const float* b2 = (const float*)d_in[6];
  const float* Wc = (const float*)d_in[7];
  const float* bc = (const float*)d_in[8];
  float* out = (float*)d_out;
  const int* srcv = ei;
  const int* dstv = ei + NE;

  char* p = (char*)d_ws;
  auto alloc = [&](size_t bytes) {
    char* r = p;
    p += (bytes + 255) & ~(size_t)255;
    return r;
  };
  int* hist2d = (int*)alloc((size_t)EB * NBK * sizeof(int));
  int* colpref = (int*)alloc((size_t)EB * NBK * sizeof(int));
  int* coltotal = (int*)alloc((size_t)NBK * sizeof(int));
  int* gstart = (int*)alloc((size_t)(NG + 1) * sizeof(int));
  int* row_start = (int*)alloc((size_t)(NN + 1) * sizeof(int));
  int* binned = (int*)alloc((size_t)NE * sizeof(int));
  unsigned short* csr_src = (unsigned short*)alloc((size_t)NE * sizeof(unsigned short));
  float* dinv = (float*)alloc((size_t)NN * sizeof(float));
  unsigned char* deg8 = (unsigned char*)alloc((size_t)NN);
  int* deghist = (int*)alloc(256 * sizeof(int));
  int* classcnt = (int*)alloc(256 * sizeof(int));
  int* perm = (int*)alloc((size_t)NN * sizeof(int));
  __half* g = (__half*)alloc((size_t)NN * DF * sizeof(__half));
  __half* h = (__half*)alloc((size_t)NN * DF * sizeof(__half));
  float* partial = (float*)alloc((size_t)NG * PC * DF * sizeof(float));

  k_hist<<<EB, 256, 0, stream>>>(dstv, hist2d);
  k_colscan<<<NBK, 256, 0, stream>>>(hist2d, colpref, coltotal, batch, gstart, deghist, classcnt);
  k_bin2<<<EB, 256, 0, stream>>>(srcv, dstv, hist2d, coltotal, colpref, binned);
  k_csr<<<NBK, 256, 0, stream>>>(binned, coltotal, dinv, row_start, csr_src, deg8, deghist);
  k_perm<<<NBK, 256, 0, stream>>>(deg8, deghist, classcnt, perm);

  k_gemm<float><<<(NN + GR - 1) / GR, 256, 0, stream>>>(x, W1, dinv, g);
  k_agg<<<NN / 16, 256, 0, stream>>>(g, dinv, b1, row_start, csr_src, perm, h);
  k_gemm<__half><<<(NN + GR - 1) / GR, 256, 0, stream>>>(h, W2, dinv, g);
  k_agg<<<NN / 16, 256, 0, stream>>>(g, dinv, b2, row_start, csr_src, perm, h);

  k_pool2<<<NG * PC, 384, 0, stream>>>(h, gstart, partial);
  k_pool3<<<NG, 128, 0, stream>>>(partial, gstart, Wc, bc, out);
}

// Round 12
// 152.467 us; speedup vs baseline: 1.8570x; 1.8570x over previous
//
#include <hip/hip_runtime.h>
#include <hip/hip_fp16.h>

#define NN 50000
#define NE 800000
#define NG 64
#define DF 96
#define SLOPE 0.2f
#define NBK 196   // (NN+255)/256 buckets of 256 dst nodes
#define EB 196    // (NE+4095)/4096 edge blocks (4096 edges per block)
#define PC 12     // pool chunks per graph

// ---------------- pass A1: per-block bucket histogram (row-major out, coalesced) ----------------
__global__ __launch_bounds__(256) void k_hist(const int* __restrict__ dst,
                                              int* __restrict__ hist2d) {
  __shared__ int h[NBK];
  int t = threadIdx.x;
  if (t < NBK) h[t] = 0;
  __syncthreads();
  int base = blockIdx.x * 4096;
  for (int k = 0; k < 16; ++k) {
    int e = base + k * 256 + t;
    if (e < NE) atomicAdd(&h[dst[e] >> 8], 1);
  }
  __syncthreads();
  if (t < NBK) hist2d[blockIdx.x * NBK + t] = h[t];
}

// ---------------- per-column exclusive scan over edge-blocks; block 0: graph bounds ----------
__global__ __launch_bounds__(256) void k_colscan(const int* __restrict__ hist2d,
                                                 int* __restrict__ colpref,
                                                 int* __restrict__ coltotal,
                                                 const int* __restrict__ batch,
                                                 int* __restrict__ gstart) {
  __shared__ int s[256];
  int col = blockIdx.x;  // bucket (column)
  int b = threadIdx.x;   // edge-block index
  int v = (b < EB) ? hist2d[b * NBK + col] : 0;
  s[b] = v;
  __syncthreads();
  for (int o = 1; o < 256; o <<= 1) {
    int u = (b >= o) ? s[b - o] : 0;
    __syncthreads();
    s[b] += u;
    __syncthreads();
  }
  if (b < EB) colpref[b * NBK + col] = s[b] - v;
  if (b == 255) coltotal[col] = s[b];
  if (blockIdx.x == 0 && b <= NG) {  // graph bounds (batch sorted)
    int g = b, lo = 0, hi = NN;
    while (lo < hi) {
      int mid = (lo + hi) >> 1;
      if (batch[mid] < g) lo = mid + 1; else hi = mid;
    }
    gstart[g] = lo;
  }
}

// ---------------- pass A2: bin edges (deterministic offsets, LDS staged) ----------------
// packed entry: src | ((dst&255)<<16)
__global__ __launch_bounds__(256) void k_bin2(const int* __restrict__ src,
                                              const int* __restrict__ dst,
                                              const int* __restrict__ hist2d,
                                              const int* __restrict__ coltotal,
                                              const int* __restrict__ colpref,
                                              int* __restrict__ binned) {
  __shared__ int h[NBK], loff[NBK], cur[NBK], gb[NBK];
  __shared__ int tmp[256];
  __shared__ int stage[4096];
  __shared__ unsigned char sbk[4096];
  int t = threadIdx.x;
  int ctv = (t < NBK) ? coltotal[t] : 0;
  tmp[t] = ctv;
  __syncthreads();
  for (int o = 1; o < 256; o <<= 1) {
    int u = (t >= o) ? tmp[t - o] : 0;
    __syncthreads();
    tmp[t] += u;
    __syncthreads();
  }
  int bbase_t = tmp[t] - ctv;  // exclusive
  if (t < NBK) h[t] = hist2d[blockIdx.x * NBK + t];
  __syncthreads();
  tmp[t] = (t < NBK) ? h[t] : 0;
  __syncthreads();
  for (int o = 1; o < 256; o <<= 1) {
    int u = (t >= o) ? tmp[t - o] : 0;
    __syncthreads();
    tmp[t] += u;
    __syncthreads();
  }
  if (t < NBK) {
    int excl = tmp[t] - h[t];
    loff[t] = excl;
    cur[t] = excl;
    gb[t] = bbase_t + colpref[blockIdx.x * NBK + t];
  }
  __syncthreads();
  int base = blockIdx.x * 4096;
  for (int k = 0; k < 16; ++k) {
    int e = base + k * 256 + t;
    if (e < NE) {
      int d = dst[e];
      int b = d >> 8;
      int p = atomicAdd(&cur[b], 1);
      stage[p] = src[e] | ((d & 255) << 16);
      sbk[p] = (unsigned char)b;
    }
  }
  __syncthreads();
  int tot = min(4096, NE - base);
  for (int i = t; i < tot; i += 256) {
    int b = sbk[i];
    binned[gb[b] + (i - loff[b])] = stage[i];
  }
}

// ---------------- pass B: per-bucket CSR build + dinv/row_start + class ranks (LDS only) --------
__global__ __launch_bounds__(256) void k_csr(const int* __restrict__ binned,
                                             const int* __restrict__ coltotal,
                                             float* __restrict__ dinv,
                                             int* __restrict__ row_start,
                                             unsigned short* __restrict__ csr_src,
                                             unsigned char* __restrict__ deg8,
                                             unsigned short* __restrict__ rank16,
                                             int* __restrict__ blockclass) {
  __shared__ int h[256], cur[256], tmp[256], dcur[256];
  int t = threadIdx.x;
  int b = blockIdx.x;
  int ctv = (t < NBK) ? coltotal[t] : 0;
  h[t] = ctv;
  tmp[t] = ctv;
  __syncthreads();
  for (int o = 1; o < 256; o <<= 1) {
    int u = (t >= o) ? tmp[t - o] : 0;
    __syncthreads();
    tmp[t] += u;
    __syncthreads();
  }
  int ebeg = tmp[b] - h[b];
  int eend = tmp[b];
  __syncthreads();
  h[t] = 0;
  dcur[t] = 0;
  __syncthreads();
  for (int i = ebeg + t; i < eend; i += 256) atomicAdd(&h[(unsigned)binned[i] >> 16], 1);
  __syncthreads();
  tmp[t] = h[t];
  __syncthreads();
  for (int o = 1; o < 256; o <<= 1) {
    int v = (t >= o) ? tmp[t - o] : 0;
    __syncthreads();
    tmp[t] += v;
    __syncthreads();
  }
  int mydeg = h[t];
  int rs = ebeg + (tmp[t] - mydeg);
  cur[t] = rs;
  int n = b * 256 + t;
  if (n < NN) {
    row_start[n] = rs;
    dinv[n] = rsqrtf((float)mydeg + 1.0f);
    int c = min(mydeg, 255);
    deg8[n] = (unsigned char)c;
    rank16[n] = (unsigned short)atomicAdd(&dcur[c], 1);  // LDS atomic only
  }
  if (b == NBK - 1 && t == 255) row_start[NN] = NE;
  __syncthreads();
  blockclass[b * 256 + t] = dcur[t];  // coalesced
  for (int i = ebeg + t; i < eend; i += 256) {
    int pr = binned[i];
    int p = atomicAdd(&cur[(unsigned)pr >> 16], 1);
    csr_src[p] = (unsigned short)(pr & 0xFFFF);
  }
}

// ---------------- per-class scan over blocks (256 blocks, no atomics) ----------------
__global__ __launch_bounds__(256) void k_cscan(const int* __restrict__ blockclass,
                                               int* __restrict__ cbpre,
                                               int* __restrict__ classtotal) {
  __shared__ int s[256];
  int c = blockIdx.x;
  int b = threadIdx.x;
  int v = (b < NBK) ? blockclass[b * 256 + c] : 0;
  s[b] = v;
  __syncthreads();
  for (int o = 1; o < 256; o <<= 1) {
    int u = (b >= o) ? s[b - o] : 0;
    __syncthreads();
    s[b] += u;
    __syncthreads();
  }
  if (b < NBK) cbpre[b * 256 + c] = s[b] - v;
  if (b == 255) classtotal[c] = s[b];
}

// ---------------- degree-sorted permutation (fully deterministic offsets) ----------------
__global__ __launch_bounds__(256) void k_perm(const unsigned char* __restrict__ deg8,
                                              const unsigned short* __restrict__ rank16,
                                              const int* __restrict__ cbpre,
                                              const int* __restrict__ classtotal,
                                              int* __restrict__ perm) {
  __shared__ int s[256];
  __shared__ int cb[256];
  int t = threadIdx.x;
  int v = classtotal[t];
  s[t] = v;
  __syncthreads();
  for (int o = 1; o < 256; o <<= 1) {
    int u = (t >= o) ? s[t - o] : 0;
    __syncthreads();
    s[t] += u;
    __syncthreads();
  }
  cb[t] = s[t] - v;  // exclusive class base
  __syncthreads();
  int n = blockIdx.x * 256 + t;
  if (n < NN) {
    int c = deg8[n];
    perm[cb[c] + cbpre[blockIdx.x * 256 + c] + rank16[n]] = n;
  }
}

// ---------------- G(fp16) = (X @ W) * dinv[row]; X fp32 or fp16, direct global reads ----------------
#define GR 64
template <typename T>
__global__ __launch_bounds__(256) void k_gemm(const T* __restrict__ X,
                                              const float* __restrict__ W,
                                              const float* __restrict__ dinv,
                                              __half* __restrict__ G) {
  __shared__ float Ws[DF * DF];  // 36.9 KB -> ~4 blocks/CU
  int t = threadIdx.x;
  for (int i = t; i < DF * DF / 4; i += 256)
    ((float4*)Ws)[i] = ((const float4*)W)[i];
  __syncthreads();
  int tc = t & 15;
  int tr = t >> 4;
  int c0 = tc * 6;
  int r0 = blockIdx.x * GR + tr * 4;
  const T* xp[4];
#pragma unroll
  for (int i = 0; i < 4; ++i) xp[i] = X + (size_t)min(r0 + i, NN - 1) * DF;

  float acc[4][6];
#pragma unroll
  for (int i = 0; i < 4; ++i)
#pragma unroll
    for (int j = 0; j < 6; ++j) acc[i][j] = 0.f;

#pragma unroll 4
  for (int k4 = 0; k4 < DF / 4; ++k4) {
    float xr[4][4];
#pragma unroll
    for (int i = 0; i < 4; ++i) {
      if constexpr (sizeof(T) == 4) {
        float4 v = ((const float4*)xp[i])[k4];
        xr[i][0] = v.x; xr[i][1] = v.y; xr[i][2] = v.z; xr[i][3] = v.w;
      } else {
        uint2 hv = ((const uint2*)xp[i])[k4];
        float2 a = __half22float2(*(__half2*)&hv.x);
        float2 b = __half22float2(*(__half2*)&hv.y);
        xr[i][0] = a.x; xr[i][1] = a.y; xr[i][2] = b.x; xr[i][3] = b.y;
      }
    }
#pragma unroll
    for (int kk = 0; kk < 4; ++kk) {
      int k = k4 * 4 + kk;
      float2 w0 = *(float2*)&Ws[k * DF + c0];
      float2 w1 = *(float2*)&Ws[k * DF + c0 + 2];
      float2 w2 = *(float2*)&Ws[k * DF + c0 + 4];
      float wv[6] = {w0.x, w0.y, w1.x, w1.y, w2.x, w2.y};
#pragma unroll
      for (int i = 0; i < 4; ++i)
#pragma unroll
        for (int j = 0; j < 6; ++j) acc[i][j] = fmaf(xr[i][kk], wv[j], acc[i][j]);
    }
  }
#pragma unroll
  for (int i = 0; i < 4; ++i) {
    int row = r0 + i;
    if (row < NN) {
      float dv = dinv[row];
      __half2* gp = (__half2*)(G + (size_t)row * DF + c0);
#pragma unroll
      for (int j = 0; j < 3; ++j)
        gp[j] = __floats2half2_rn(acc[i][2 * j] * dv, acc[i][2 * j + 1] * dv);
    }
  }
}

// ---------------- gather-aggregate: 16 lanes/node (6 feats/lane, 12B loads), degree-sorted ------
__global__ __launch_bounds__(256) void k_agg(const __half* __restrict__ G,
                                             const float* __restrict__ dinv,
                                             const float* __restrict__ bias,
                                             const int* __restrict__ row_start,
                                             const unsigned short* __restrict__ csr_src,
                                             const int* __restrict__ perm,
                                             __half* __restrict__ H) {
  int lane = threadIdx.x & 15;
  int n = perm[blockIdx.x * 16 + (threadIdx.x >> 4)];  // NN = 16*3125 exact
  const char* Gb = (const char*)G;
  uint3 sv = *(const uint3*)(Gb + (size_t)n * 192 + lane * 12);
  float2 f0 = __half22float2(*(__half2*)&sv.x);
  float2 f1 = __half22float2(*(__half2*)&sv.y);
  float2 f2 = __half22float2(*(__half2*)&sv.z);
  float a0 = f0.x, a1 = f0.y, a2 = f1.x, a3 = f1.y, a4 = f2.x, a5 = f2.y;

  int s = row_start[n], e = row_start[n + 1];
  for (int j0 = s; j0 < e; j0 += 16) {
    int my = (j0 + lane < e) ? (int)csr_src[j0 + lane] : 0;
    int cnt = min(16, e - j0);
    int jj = 0;
    for (; jj + 8 <= cnt; jj += 8) {
      uint3 u[8];
#pragma unroll
      for (int q = 0; q < 8; ++q)
        u[q] = *(const uint3*)(Gb + (size_t)__shfl(my, jj + q, 16) * 192 + lane * 12);
#pragma unroll
      for (int q = 0; q < 8; ++q) {
        float2 g0 = __half22float2(*(__half2*)&u[q].x);
        float2 g1 = __half22float2(*(__half2*)&u[q].y);
        float2 g2 = __half22float2(*(__half2*)&u[q].z);
        a0 += g0.x; a1 += g0.y; a2 += g1.x; a3 += g1.y; a4 += g2.x; a5 += g2.y;
      }
    }
    for (; jj < cnt; ++jj) {
      uint3 u = *(const uint3*)(Gb + (size_t)__shfl(my, jj, 16) * 192 + lane * 12);
      float2 g0 = __half22float2(*(__half2*)&u.x);
      float2 g1 = __half22float2(*(__half2*)&u.y);
      float2 g2 = __half22float2(*(__half2*)&u.z);
      a0 += g0.x; a1 += g0.y; a2 += g1.x; a3 += g1.y; a4 += g2.x; a5 += g2.y;
    }
  }
  float dv = dinv[n];
  float2 b0 = *(const float2*)(bias + 6 * lane);
  float2 b1 = *(const float2*)(bias + 6 * lane + 2);
  float2 b2 = *(const float2*)(bias + 6 * lane + 4);
  float v0 = dv * a0 + b0.x, v1 = dv * a1 + b0.y;
  float v2 = dv * a2 + b1.x, v3 = dv * a3 + b1.y;
  float v4 = dv * a4 + b2.x, v5 = dv * a5 + b2.y;
  v0 = v0 > 0.f ? v0 : SLOPE * v0;
  v1 = v1 > 0.f ? v1 : SLOPE * v1;
  v2 = v2 > 0.f ? v2 : SLOPE * v2;
  v3 = v3 > 0.f ? v3 : SLOPE * v3;
  v4 = v4 > 0.f ? v4 : SLOPE * v4;
  v5 = v5 > 0.f ? v5 : SLOPE * v5;
  uint3 o;
  *(__half2*)&o.x = __floats2half2_rn(v0, v1);
  *(__half2*)&o.y = __floats2half2_rn(v2, v3);
  *(__half2*)&o.z = __floats2half2_rn(v4, v5);
  *(uint3*)((char*)H + (size_t)n * 192 + lane * 12) = o;
}

// ---------------- pool stage 1: 12 chunks per graph (fp16 in, fp32 partials) ----------------
__global__ __launch_bounds__(384) void k_pool2(const __half* __restrict__ H,
                                               const int* __restrict__ gstart,
                                               float* __restrict__ partial) {
  int g = blockIdx.x / PC, c = blockIdx.x % PC;
  int f2 = threadIdx.x % 48;
  int r = threadIdx.x / 48;
  int s = gstart[g], e = gstart[g + 1];
  int len = (e - s + PC - 1) / PC;
  int cs = s + c * len, ce = min(cs + len, e);
  float ax = 0.f, ay = 0.f;
  for (int n = cs + r; n < ce; n += 8) {
    float2 v = __half22float2(((const __half2*)(H + (size_t)n * DF))[f2]);
    ax += v.x;
    ay += v.y;
  }
  __shared__ float2 red[8][48];
  red[r][f2] = float2{ax, ay};
  __syncthreads();
  if (r == 0) {
    float sx = 0.f, sy = 0.f;
#pragma unroll
    for (int q = 0; q < 8; ++q) { sx += red[q][f2].x; sy += red[q][f2].y; }
    partial[(size_t)blockIdx.x * DF + 2 * f2] = sx;
    partial[(size_t)blockIdx.x * DF + 2 * f2 + 1] = sy;
  }
}

// ---------------- pool stage 2 + classifier ----------------
__global__ __launch_bounds__(128) void k_pool3(const float* __restrict__ partial,
                                               const int* __restrict__ gstart,
                                               const float* __restrict__ Wc,
                                               const float* __restrict__ bc,
                                               float* __restrict__ out) {
  __shared__ float pm[DF];
  int g = blockIdx.x;
  int t = threadIdx.x;
  if (t < DF) {
    float s = 0.f;
    for (int c = 0; c < PC; ++c) s += partial[(size_t)(g * PC + c) * DF + t];
    float cnt = (float)(gstart[g + 1] - gstart[g]);
    pm[t] = s / fmaxf(cnt, 1.0f);
  }
  __syncthreads();
  if (t < 2) {
    float s = 0.f;
    for (int c = 0; c < DF; ++c) s += pm[c] * Wc[c * 2 + t];
    out[g * 2 + t] = s + bc[t];
  }
}

extern "C" void kernel_launch(void* const* d_in, const int* in_sizes, int n_in,
                              void* d_out, int out_size, void* d_ws, size_t ws_size,
                              hipStream_t stream) {
  const float* x = (const float*)d_in[0];
  const int* ei = (const int*)d_in[1];
  const int* batch = (const int*)d_in[2];
  const float* W1 = (const float*)d_in[3];
  const float* b1 = (const float*)d_in[4];
  const float* W2 = (const float*)d_in[5];
  const float* b2 = (const float*)d_in[6];
  const float* Wc = (const float*)d_in[7];
  const float* bc = (const float*)d_in[8];
  float* out = (float*)d_out;
  const int* srcv = ei;
  const int* dstv = ei + NE;

  char* p = (char*)d_ws;
  auto alloc = [&](size_t bytes) {
    char* r = p;
    p += (bytes + 255) & ~(size_t)255;
    return r;
  };
  int* hist2d = (int*)alloc((size_t)EB * NBK * sizeof(int));
  int* colpref = (int*)alloc((size_t)EB * NBK * sizeof(int));
  int* coltotal = (int*)alloc((size_t)NBK * sizeof(int));
  int* gstart = (int*)alloc((size_t)(NG + 1) * sizeof(int));
  int* row_start = (int*)alloc((size_t)(NN + 1) * sizeof(int));
  int* binned = (int*)alloc((size_t)NE * sizeof(int));
  unsigned short* csr_src = (unsigned short*)alloc((size_t)NE * sizeof(unsigned short));
  float* dinv = (float*)alloc((size_t)NN * sizeof(float));
  unsigned char* deg8 = (unsigned char*)alloc((size_t)NN);
  unsigned short* rank16 = (unsigned short*)alloc((size_t)NN * sizeof(unsigned short));
  int* blockclass = (int*)alloc((size_t)NBK * 256 * sizeof(int));
  int* cbpre = (int*)alloc((size_t)NBK * 256 * sizeof(int));
  int* classtotal = (int*)alloc(256 * sizeof(int));
  int* perm = (int*)alloc((size_t)NN * sizeof(int));
  __half* g = (__half*)alloc((size_t)NN * DF * sizeof(__half));
  __half* h = (__half*)alloc((size_t)NN * DF * sizeof(__half));
  float* partial = (float*)alloc((size_t)NG * PC * DF * sizeof(float));

  k_hist<<<EB, 256, 0, stream>>>(dstv, hist2d);
  k_colscan<<<NBK, 256, 0, stream>>>(hist2d, colpref, coltotal, batch, gstart);
  k_bin2<<<EB, 256, 0, stream>>>(srcv, dstv, hist2d, coltotal, colpref, binned);
  k_csr<<<NBK, 256, 0, stream>>>(binned, coltotal, dinv, row_start, csr_src, deg8, rank16, blockclass);
  k_cscan<<<256, 256, 0, stream>>>(blockclass, cbpre, classtotal);
  k_perm<<<NBK, 256, 0, stream>>>(deg8, rank16, cbpre, classtotal, perm);

  k_gemm<float><<<(NN + GR - 1) / GR, 256, 0, stream>>>(x, W1, dinv, g);
  k_agg<<<NN / 16, 256, 0, stream>>>(g, dinv, b1, row_start, csr_src, perm, h);
  k_gemm<__half><<<(NN + GR - 1) / GR, 256, 0, stream>>>(h, W2, dinv, g);
  k_agg<<<NN / 16, 256, 0, stream>>>(g, dinv, b2, row_start, csr_src, perm, h);

  k_pool2<<<NG * PC, 384, 0, stream>>>(h, gstart, partial);
  k_pool3<<<NG, 128, 0, stream>>>(partial, gstart, Wc, bc, out);
}